// Round 4
// baseline (1560.627 us; speedup 1.0000x reference)
//
#include <hip/hip_runtime.h>
#include <cstddef>

#define NN 256
#define DD 1024
#define CC 4
#define RS 16              // row-split partials per node
#define ROWS (DD / RS)     // 64 rows per unit
#define NB 448             // < 2 blocks/CU capacity -> all blocks resident
#define ROOT (NN - 1)

// Static device scratch. g_done/g_ucnt are ALWAYS left zeroed at kernel exit
// (reset by the completing block), so each launch/replay starts clean.
__device__ float g_zp[NN][RS][DD];  // row-partial sums of z per node
__device__ int g_done[NN];          // completed partials per node (0..16)
__device__ int g_ucnt;              // completed units (global)

__device__ __forceinline__ float4 relu4(float4 v) {
  float4 r;
  r.x = fmaxf(v.x, 0.f); r.y = fmaxf(v.y, 0.f);
  r.z = fmaxf(v.z, 0.f); r.w = fmaxf(v.w, 0.f);
  return r;
}

template <int NC>
__device__ __forceinline__ float4 run_rows(const float* const* pp, const float4* uu,
                                           const float* xs) {
  float4 acc = {0.f, 0.f, 0.f, 0.f};
#pragma unroll 8
  for (int r = 0; r < ROWS; ++r) {
    float4 a0 = *(const float4*)(pp[0] + (size_t)r * DD);
    float4 m;
    m.x = a0.x * uu[0].x; m.y = a0.y * uu[0].y;
    m.z = a0.z * uu[0].z; m.w = a0.w * uu[0].w;
#pragma unroll
    for (int c = 1; c < NC; ++c) {
      float4 a = *(const float4*)(pp[c] + (size_t)r * DD);
      m.x = fmaxf(m.x, a.x * uu[c].x);
      m.y = fmaxf(m.y, a.y * uu[c].y);
      m.z = fmaxf(m.z, a.z * uu[c].z);
      m.w = fmaxf(m.w, a.w * uu[c].w);
    }
    const float xr = xs[r];
    acc.x = fmaf(xr, m.x, acc.x);
    acc.y = fmaf(xr, m.y, acc.y);
    acc.z = fmaf(xr, m.z, acc.z);
    acc.w = fmaf(xr, m.w, acc.w);
  }
  return acc;
}

__global__ __launch_bounds__(256, 2) void dep_enc_kernel(
    const float* __restrict__ emb, const float* __restrict__ par,
    const int* __restrict__ cidx, const int* __restrict__ cdep,
    const unsigned char* __restrict__ cmask, float* __restrict__ out) {
  __shared__ int s_ci[NN][CC];
  __shared__ int s_cd[NN][CC];
  __shared__ int s_nc[NN];
  __shared__ short s_int[NN];  // internal nodes in (topological) index order
  __shared__ int s_NI;
  __shared__ int s_flag;
  __shared__ float xs[ROWS];

  const int tid = threadIdx.x;

  // ---- Phase 1 (redundant per block, ~2 us): compact children ----
  if (tid == 0)
    s_flag = (cmask[1021] == 1 && cmask[1022] == 1 && cmask[1023] == 1);
  __syncthreads();
  const bool m_u8 = (s_flag != 0);
  const int* m32 = (const int*)cmask;
  {
    const int i = tid;  // one node per thread
    int nc = 0;
#pragma unroll
    for (int c = 0; c < CC; ++c) {
      bool mk = m_u8 ? (cmask[i * CC + c] != 0) : (m32[i * CC + c] != 0);
      if (mk) {
        s_ci[i][nc] = cidx[i * CC + c];
        s_cd[i][nc] = cdep[i * CC + c];
        ++nc;
      }
    }
    s_nc[i] = nc;
  }
  __syncthreads();
  if (tid == 0) {
    int k = 0;
    for (int n = 0; n < NN; ++n)
      if (s_nc[n] > 0) s_int[k++] = (short)n;
    s_NI = k;
  }
  __syncthreads();
  const int NU = s_NI << 4;  // total units
  const int j0 = tid << 2;   // 4 columns per thread

  // ---- Phase 2: event-driven units, topological static assignment ----
  for (int g = blockIdx.x; g < NU; g += NB) {
    const int node = s_int[g >> 4];
    const int rblk = g & (RS - 1);
    const int nnc = s_nc[node];

    // Wait for internal children (thread 0 only; relaxed polls)
    if (tid == 0) {
      for (int c = 0; c < nnc; ++c) {
        const int chd = s_ci[node][c];
        if (s_nc[chd] > 0) {
          while (__hip_atomic_load(&g_done[chd], __ATOMIC_RELAXED,
                                   __HIP_MEMORY_SCOPE_AGENT) < RS)
            __builtin_amdgcn_s_sleep(1);
        }
      }
    }
    __syncthreads();  // (A) children ready; xs safe to overwrite
    if (tid < ROWS) xs[tid] = emb[(size_t)node * DD + rblk * ROWS + tid];

    // Gather relu(z_child) at this thread's 4 columns (static unroll: no scratch)
    float4 uu[CC];
    const float* pp[CC];
    const size_t rb = (size_t)(rblk * ROWS) * DD + j0;
#pragma unroll
    for (int c = 0; c < CC; ++c) {
      if (c < nnc) {
        const int chd = s_ci[node][c];
        pp[c] = par + (size_t)s_cd[node][c] * (DD * DD) + rb;
        float4 sz;
        if (s_nc[chd] == 0) {
          sz = *(const float4*)(emb + (size_t)chd * DD + j0);
        } else {
          int dmy = __hip_atomic_load(&g_done[chd], __ATOMIC_ACQUIRE,
                                      __HIP_MEMORY_SCOPE_AGENT);
          asm volatile("" ::"v"(dmy));  // keep acquire; pairs with producer release
          const float* zb = &g_zp[chd][0][j0];
          sz = *(const float4*)zb;
#pragma unroll
          for (int p = 1; p < RS; ++p) {
            float4 t = *(const float4*)(zb + (size_t)p * DD);
            sz.x += t.x; sz.y += t.y; sz.z += t.z; sz.w += t.w;
          }
        }
        uu[c] = relu4(sz);
      }
    }
    __syncthreads();  // (B) xs ready

    float4 acc;
    switch (nnc) {
      case 1: acc = run_rows<1>(pp, uu, xs); break;
      case 2: acc = run_rows<2>(pp, uu, xs); break;
      case 3: acc = run_rows<3>(pp, uu, xs); break;
      default: acc = run_rows<4>(pp, uu, xs); break;
    }
    *(float4*)(&g_zp[node][rblk][j0]) = acc;
    __syncthreads();  // (C) drains each wave's stores (vmcnt0 before s_barrier)

    if (tid == 0) {
      __hip_atomic_fetch_add(&g_done[node], 1, __ATOMIC_RELEASE,
                             __HIP_MEMORY_SCOPE_AGENT);
      int oldu = __hip_atomic_fetch_add(&g_ucnt, 1, __ATOMIC_ACQ_REL,
                                        __HIP_MEMORY_SCOPE_AGENT);
      s_flag = (oldu == NU - 1) ? 1 : 0;
    }
    __syncthreads();  // (D)

    if (s_flag) {
      // Globally-last unit: every unit (incl. all of root's) is complete.
      int dmy = __hip_atomic_load(&g_done[ROOT], __ATOMIC_ACQUIRE,
                                  __HIP_MEMORY_SCOPE_AGENT);
      asm volatile("" ::"v"(dmy));
      const float* zb = &g_zp[ROOT][0][j0];
      float4 v = *(const float4*)zb;
#pragma unroll
      for (int p = 1; p < RS; ++p) {
        float4 t = *(const float4*)(zb + (size_t)p * DD);
        v.x += t.x; v.y += t.y; v.z += t.z; v.w += t.w;
      }
      *(float4*)(out + j0) = v;
      // Reset flags for the next launch/replay (no one reads them anymore).
      g_done[tid] = 0;
      if (tid == 0) g_ucnt = 0;
    }
  }
}

extern "C" void kernel_launch(void* const* d_in, const int* in_sizes, int n_in,
                              void* d_out, int out_size, void* d_ws, size_t ws_size,
                              hipStream_t stream) {
  const float* emb = (const float*)d_in[0];
  const float* par = (const float*)d_in[1];
  const int* cidx = (const int*)d_in[2];
  const int* cdep = (const int*)d_in[3];
  const unsigned char* cmask = (const unsigned char*)d_in[4];
  float* out = (float*)d_out;

  hipLaunchKernelGGL(dep_enc_kernel, dim3(NB), dim3(256), 0, stream, emb, par,
                     cidx, cdep, cmask, out);
}

// Round 5
// 1375.723 us; speedup vs baseline: 1.1344x; 1.1344x over previous
//
#include <hip/hip_runtime.h>
#include <cstddef>

#define NN 256
#define DD 1024
#define CC 4
#define RS 16              // row-split partials per node
#define ROWS (DD / RS)     // 64 rows per unit
#define NB 448             // <= 2 blocks/CU capacity -> all blocks resident
#define ROOT (NN - 1)

// Static device scratch. Flags are ALWAYS left zeroed at kernel exit (reset by
// the globally-last unit), so every launch/graph-replay starts clean.
__device__ float g_zp[NN][RS][DD];  // row-partial sums of z per node (16 MB)
__device__ float g_z[NN][DD];       // reduced z per node (1 MB)
__device__ int g_done[NN];          // completed partials per node (0..RS)
__device__ int g_rdy[NN];           // node reduced & published
__device__ int g_ucnt;              // completed units (global)

#define AL(p) __hip_atomic_load((p), __ATOMIC_RELAXED, __HIP_MEMORY_SCOPE_AGENT)
#define AS(p, v) __hip_atomic_store((p), (v), __ATOMIC_RELAXED, __HIP_MEMORY_SCOPE_AGENT)

__device__ __forceinline__ float4 relu4(float4 v) {
  float4 r;
  r.x = fmaxf(v.x, 0.f); r.y = fmaxf(v.y, 0.f);
  r.z = fmaxf(v.z, 0.f); r.w = fmaxf(v.w, 0.f);
  return r;
}

template <int NC>
__device__ __forceinline__ float4 run_rows(const float* const* pp, const float4* uu,
                                           const float* xs) {
  float4 acc = {0.f, 0.f, 0.f, 0.f};
#pragma unroll 8
  for (int r = 0; r < ROWS; ++r) {
    float4 a0 = *(const float4*)(pp[0] + (size_t)r * DD);
    float4 m;
    m.x = a0.x * uu[0].x; m.y = a0.y * uu[0].y;
    m.z = a0.z * uu[0].z; m.w = a0.w * uu[0].w;
#pragma unroll
    for (int c = 1; c < NC; ++c) {
      float4 a = *(const float4*)(pp[c] + (size_t)r * DD);
      m.x = fmaxf(m.x, a.x * uu[c].x);
      m.y = fmaxf(m.y, a.y * uu[c].y);
      m.z = fmaxf(m.z, a.z * uu[c].z);
      m.w = fmaxf(m.w, a.w * uu[c].w);
    }
    const float xr = xs[r];
    acc.x = fmaf(xr, m.x, acc.x);
    acc.y = fmaf(xr, m.y, acc.y);
    acc.z = fmaf(xr, m.z, acc.z);
    acc.w = fmaf(xr, m.w, acc.w);
  }
  return acc;
}

__global__ __launch_bounds__(256, 2) void dep_enc_kernel(
    const float* __restrict__ emb, const float* __restrict__ par,
    const int* __restrict__ cidx, const int* __restrict__ cdep,
    const unsigned char* __restrict__ cmask, float* __restrict__ out) {
  __shared__ int s_ci[NN][CC];
  __shared__ int s_cd[NN][CC];
  __shared__ int s_nc[NN];
  __shared__ short s_int[NN];  // internal nodes in (topological) index order
  __shared__ int s_NI;
  __shared__ int s_msk;
  __shared__ int s_fin;
  __shared__ int s_last;
  __shared__ float xs[ROWS];

  const int tid = threadIdx.x;

  // ---- Phase 1 (redundant per block, ~2 us): compact children ----
  if (tid == 0)
    s_msk = (cmask[1021] == 1 && cmask[1022] == 1 && cmask[1023] == 1);
  __syncthreads();
  const bool m_u8 = (s_msk != 0);
  const int* m32 = (const int*)cmask;
  {
    const int i = tid;  // one node per thread
    int nc = 0;
#pragma unroll
    for (int c = 0; c < CC; ++c) {
      bool mk = m_u8 ? (cmask[i * CC + c] != 0) : (m32[i * CC + c] != 0);
      if (mk) {
        s_ci[i][nc] = cidx[i * CC + c];
        s_cd[i][nc] = cdep[i * CC + c];
        ++nc;
      }
    }
    s_nc[i] = nc;
  }
  __syncthreads();
  if (tid == 0) {
    int k = 0;
    for (int n = 0; n < NN; ++n)
      if (s_nc[n] > 0) s_int[k++] = (short)n;
    s_NI = k;
  }
  __syncthreads();
  const int NU = s_NI << 4;  // total units
  const int j0 = tid << 2;   // 4 columns per thread

  // ---- Phase 2: event-driven units, topological static assignment ----
  for (int g = blockIdx.x; g < NU; g += NB) {
    const int node = s_int[g >> 4];
    const int rblk = g & (RS - 1);
    const int nnc = s_nc[node];

    // Wait for internal children (thread 0; relaxed polls -> no cache inv)
    if (tid == 0) {
      for (int c = 0; c < nnc; ++c) {
        const int chd = s_ci[node][c];
        if (s_nc[chd] > 0) {
          while (AL(&g_rdy[chd]) == 0) __builtin_amdgcn_s_sleep(1);
        }
      }
    }
    __syncthreads();  // (A) children ready; prev unit fully done -> xs reusable
    if (tid < ROWS) xs[tid] = emb[(size_t)node * DD + rblk * ROWS + tid];

    // Gather relu(z_child) at this thread's 4 columns
    float4 uu[CC];
    const float* pp[CC];
    const size_t rb = (size_t)(rblk * ROWS) * DD + j0;
#pragma unroll
    for (int c = 0; c < CC; ++c) {
      if (c < nnc) {
        const int chd = s_ci[node][c];
        pp[c] = par + (size_t)s_cd[node][c] * (DD * DD) + rb;
        float4 sz;
        if (s_nc[chd] == 0) {
          sz = *(const float4*)(emb + (size_t)chd * DD + j0);
        } else {
          sz.x = AL(&g_z[chd][j0 + 0]);
          sz.y = AL(&g_z[chd][j0 + 1]);
          sz.z = AL(&g_z[chd][j0 + 2]);
          sz.w = AL(&g_z[chd][j0 + 3]);
        }
        uu[c] = relu4(sz);
      }
    }
    __syncthreads();  // (B) xs ready

    float4 acc;
    switch (nnc) {
      case 1: acc = run_rows<1>(pp, uu, xs); break;
      case 2: acc = run_rows<2>(pp, uu, xs); break;
      case 3: acc = run_rows<3>(pp, uu, xs); break;
      default: acc = run_rows<4>(pp, uu, xs); break;
    }
    // Publish partial via write-through coherent stores
    AS(&g_zp[node][rblk][j0 + 0], acc.x);
    AS(&g_zp[node][rblk][j0 + 1], acc.y);
    AS(&g_zp[node][rblk][j0 + 2], acc.z);
    AS(&g_zp[node][rblk][j0 + 3], acc.w);
    __syncthreads();  // (C) all waves' stores drained (vmcnt0 before s_barrier)

    if (tid == 0) {
      int old = __hip_atomic_fetch_add(&g_done[node], 1, __ATOMIC_RELEASE,
                                       __HIP_MEMORY_SCOPE_AGENT);
      s_fin = (old == RS - 1) ? 1 : 0;
    }
    __syncthreads();  // (D)

    if (s_fin) {
      // Finisher: reduce 16 partials in FIXED order (deterministic), publish.
      float4 v = {0.f, 0.f, 0.f, 0.f};
#pragma unroll
      for (int p = 0; p < RS; ++p) {
        v.x += AL(&g_zp[node][p][j0 + 0]);
        v.y += AL(&g_zp[node][p][j0 + 1]);
        v.z += AL(&g_zp[node][p][j0 + 2]);
        v.w += AL(&g_zp[node][p][j0 + 3]);
      }
      AS(&g_z[node][j0 + 0], v.x);
      AS(&g_z[node][j0 + 1], v.y);
      AS(&g_z[node][j0 + 2], v.z);
      AS(&g_z[node][j0 + 3], v.w);
      if (node == ROOT) *(float4*)(out + j0) = v;
      __syncthreads();  // (E) finisher stores drained
      if (tid == 0)
        __hip_atomic_fetch_add(&g_rdy[node], 1, __ATOMIC_RELEASE,
                               __HIP_MEMORY_SCOPE_AGENT);
    }

    if (tid == 0) {
      int oldu = __hip_atomic_fetch_add(&g_ucnt, 1, __ATOMIC_RELEASE,
                                        __HIP_MEMORY_SCOPE_AGENT);
      s_last = (oldu == NU - 1) ? 1 : 0;
    }
    __syncthreads();  // (F)

    if (s_last) {
      // Globally-last unit: everything complete. Reset flags for next replay.
      AS(&g_done[tid], 0);
      AS(&g_rdy[tid], 0);
      if (tid == 0) AS(&g_ucnt, 0);
    }
  }
}

extern "C" void kernel_launch(void* const* d_in, const int* in_sizes, int n_in,
                              void* d_out, int out_size, void* d_ws, size_t ws_size,
                              hipStream_t stream) {
  const float* emb = (const float*)d_in[0];
  const float* par = (const float*)d_in[1];
  const int* cidx = (const int*)d_in[2];
  const int* cdep = (const int*)d_in[3];
  const unsigned char* cmask = (const unsigned char*)d_in[4];
  float* out = (float*)d_out;

  hipLaunchKernelGGL(dep_enc_kernel, dim3(NB), dim3(256), 0, stream, emb, par,
                     cidx, cdep, cmask, out);
}

// Round 6
// 709.439 us; speedup vs baseline: 2.1998x; 1.9392x over previous
//
#include <hip/hip_runtime.h>
#include <cstddef>

#define NN 256
#define DD 1024
#define CC 4
#define RS 16              // row-split units per node
#define ROWS (DD / RS)     // 64 rows per unit
#define NB 448             // <= 2 blocks/CU capacity -> all blocks resident
#define LEAVES 32
#define LQUOTA (NB / LEAVES)  // 14 arrivals per leaf counter
#define ROOT (NN - 1)
#define AGT __HIP_MEMORY_SCOPE_AGENT

// Static device scratch. ALL of it is left zeroed at kernel exit (g_z zeroed by
// the cleanup stage, counters by the last arriver), so replays start clean.
__device__ float g_z[NN][DD];      // accumulated z per node (1 MB)
__device__ int g_bar_leaf[LEAVES]; // barrier leaf counters
__device__ int g_bar_root;         // barrier root counter
__device__ int g_bar_gen;          // barrier generation word

#define AL(p) __hip_atomic_load((p), __ATOMIC_RELAXED, AGT)
#define ASR(p, v) __hip_atomic_store((p), (v), __ATOMIC_RELAXED, AGT)

__device__ __forceinline__ void grid_bar(int gen) {
  __syncthreads();  // drains this block's vmem (incl. atomics) before arrival
  if (threadIdx.x == 0) {
    const int leaf = blockIdx.x & (LEAVES - 1);
    int lo = __hip_atomic_fetch_add(&g_bar_leaf[leaf], 1, __ATOMIC_RELAXED, AGT);
    if (lo == LQUOTA - 1) {
      int ro = __hip_atomic_fetch_add(&g_bar_root, 1, __ATOMIC_RELAXED, AGT);
      if (ro == LEAVES - 1) {
        for (int i = 0; i < LEAVES; ++i) ASR(&g_bar_leaf[i], 0);
        ASR(&g_bar_root, 0);
        // release: counter resets visible before gen flips
        __hip_atomic_store(&g_bar_gen, gen, __ATOMIC_RELEASE, AGT);
      } else {
        while (AL(&g_bar_gen) < gen) __builtin_amdgcn_s_sleep(8);
      }
    } else {
      while (AL(&g_bar_gen) < gen) __builtin_amdgcn_s_sleep(8);
    }
  }
  __syncthreads();
}

__device__ __forceinline__ void grid_collect() {  // final: count arrivals, reset, no wait
  __syncthreads();
  if (threadIdx.x == 0) {
    const int leaf = blockIdx.x & (LEAVES - 1);
    int lo = __hip_atomic_fetch_add(&g_bar_leaf[leaf], 1, __ATOMIC_RELAXED, AGT);
    if (lo == LQUOTA - 1) {
      int ro = __hip_atomic_fetch_add(&g_bar_root, 1, __ATOMIC_RELAXED, AGT);
      if (ro == LEAVES - 1) {
        for (int i = 0; i < LEAVES; ++i) ASR(&g_bar_leaf[i], 0);
        ASR(&g_bar_root, 0);
        ASR(&g_bar_gen, 0);
      }
    }
  }
}

__device__ __forceinline__ float4 relu4(float4 v) {
  float4 r;
  r.x = fmaxf(v.x, 0.f); r.y = fmaxf(v.y, 0.f);
  r.z = fmaxf(v.z, 0.f); r.w = fmaxf(v.w, 0.f);
  return r;
}

template <int NC>
__device__ __forceinline__ float4 run_rows(const float* const* pp, const float4* uu,
                                           const float* xs) {
  float4 acc = {0.f, 0.f, 0.f, 0.f};
#pragma unroll 8
  for (int r = 0; r < ROWS; ++r) {
    float4 a0 = *(const float4*)(pp[0] + (size_t)r * DD);
    float4 m;
    m.x = a0.x * uu[0].x; m.y = a0.y * uu[0].y;
    m.z = a0.z * uu[0].z; m.w = a0.w * uu[0].w;
#pragma unroll
    for (int c = 1; c < NC; ++c) {
      float4 a = *(const float4*)(pp[c] + (size_t)r * DD);
      m.x = fmaxf(m.x, a.x * uu[c].x);
      m.y = fmaxf(m.y, a.y * uu[c].y);
      m.z = fmaxf(m.z, a.z * uu[c].z);
      m.w = fmaxf(m.w, a.w * uu[c].w);
    }
    const float xr = xs[r];
    acc.x = fmaf(xr, m.x, acc.x);
    acc.y = fmaf(xr, m.y, acc.y);
    acc.z = fmaf(xr, m.z, acc.z);
    acc.w = fmaf(xr, m.w, acc.w);
  }
  return acc;
}

__global__ __launch_bounds__(256, 2) void dep_enc_kernel(
    const float* __restrict__ emb, const float* __restrict__ par,
    const int* __restrict__ cidx, const int* __restrict__ cdep,
    const unsigned char* __restrict__ cmask, float* __restrict__ out) {
  __shared__ int s_ci[NN][CC];
  __shared__ int s_cd[NN][CC];
  __shared__ int s_nc[NN];
  __shared__ int s_lvl[NN];
  __shared__ int s_cur[NN];
  __shared__ int s_lst[NN + 2];
  __shared__ unsigned char s_reach[NN];
  __shared__ short s_ord[NN];
  __shared__ int s_nlev;
  __shared__ int s_flag;
  __shared__ float xs[ROWS];

  const int tid = threadIdx.x;

  // ---- Phase 1 (redundant per block, ~5 us): schedule build in LDS ----
  if (tid == 0)
    s_flag = (cmask[1021] == 1 && cmask[1022] == 1 && cmask[1023] == 1);
  __syncthreads();
  const bool m_u8 = (s_flag != 0);
  const int* m32 = (const int*)cmask;
  const int i = tid;  // one node per thread
  int nc = 0;
#pragma unroll
  for (int c = 0; c < CC; ++c) {
    bool mk = m_u8 ? (cmask[i * CC + c] != 0) : (m32[i * CC + c] != 0);
    if (mk) {
      s_ci[i][nc] = cidx[i * CC + c];
      s_cd[i][nc] = cdep[i * CC + c];
      ++nc;
    }
  }
  s_nc[i] = nc;
  s_lvl[i] = 0;
  s_reach[i] = (i == ROOT) ? 1 : 0;
  __syncthreads();

  // Level fixpoint (monotone; converges in <= depth passes)
  for (int it = 0; it < NN + 2; ++it) {
    if (tid == 0) s_flag = 0;
    __syncthreads();
    if (nc) {
      int lv = 0;
      for (int c = 0; c < nc; ++c) lv = max(lv, s_lvl[s_ci[i][c]]);
      lv += 1;
      if (lv != s_lvl[i]) { s_lvl[i] = lv; s_flag = 1; }
    }
    __syncthreads();
    int ch = s_flag;
    __syncthreads();
    if (!ch) break;
  }

  // Reachability fixpoint (root downward)
  for (int it = 0; it < NN + 2; ++it) {
    if (tid == 0) s_flag = 0;
    __syncthreads();
    if (s_reach[i] && nc) {
      for (int c = 0; c < nc; ++c)
        if (!s_reach[s_ci[i][c]]) { s_reach[s_ci[i][c]] = 1; s_flag = 1; }
    }
    __syncthreads();
    int ch = s_flag;
    __syncthreads();
    if (!ch) break;
  }

  // Deterministic bucket build (tid0 serial over LDS; identical in every block)
  if (tid == 0) {
    for (int L = 0; L < NN + 2; ++L) s_lst[L] = 0;
    int maxl = 0;
    for (int n = 0; n < NN; ++n)
      if (s_reach[n] && s_nc[n] > 0) {
        s_lst[s_lvl[n] + 1]++;
        if (s_lvl[n] > maxl) maxl = s_lvl[n];
      }
    for (int L = 1; L <= maxl + 1; ++L) s_lst[L] += s_lst[L - 1];
    for (int L = 0; L <= maxl + 1; ++L) s_cur[L] = s_lst[L];
    for (int n = 0; n < NN; ++n)
      if (s_reach[n] && s_nc[n] > 0) s_ord[s_cur[s_lvl[n]]++] = (short)n;
    s_nlev = maxl;
  }
  __syncthreads();
  const int nlev = s_nlev;
  const int j0 = tid << 2;  // 4 consecutive columns per thread

  // ---- Phase 2: level-synchronized sweep with cheap barriers ----
  for (int L = 1; L <= nlev; ++L) {
    const int s = s_lst[L];
    const int nunits = (s_lst[L + 1] - s) << 4;  // RS units per node
    for (int g = blockIdx.x; g < nunits; g += NB) {
      const int node = s_ord[s + (g >> 4)];
      const int rblk = g & (RS - 1);
      const int nnc = s_nc[node];

      __syncthreads();  // xs from previous unit fully consumed
      if (tid < ROWS) xs[tid] = emb[(size_t)node * DD + rblk * ROWS + tid];

      // Gather relu(z_child) at this thread's 4 columns
      float4 uu[CC];
      const float* pp[CC];
      const size_t rb = (size_t)(rblk * ROWS) * DD + j0;
#pragma unroll
      for (int c = 0; c < CC; ++c) {
        if (c < nnc) {
          const int chd = s_ci[node][c];
          pp[c] = par + (size_t)s_cd[node][c] * (DD * DD) + rb;
          float4 sz;
          if (s_nc[chd] == 0) {
            sz = *(const float4*)(emb + (size_t)chd * DD + j0);
          } else {
            sz.x = AL(&g_z[chd][j0 + 0]);
            sz.y = AL(&g_z[chd][j0 + 1]);
            sz.z = AL(&g_z[chd][j0 + 2]);
            sz.w = AL(&g_z[chd][j0 + 3]);
          }
          uu[c] = relu4(sz);
        }
      }
      __syncthreads();  // xs ready

      float4 acc;
      switch (nnc) {
        case 1: acc = run_rows<1>(pp, uu, xs); break;
        case 2: acc = run_rows<2>(pp, uu, xs); break;
        case 3: acc = run_rows<3>(pp, uu, xs); break;
        default: acc = run_rows<4>(pp, uu, xs); break;
      }
      // Accumulate partial into z at the memory-side coherence point
      __hip_atomic_fetch_add(&g_z[node][j0 + 0], acc.x, __ATOMIC_RELAXED, AGT);
      __hip_atomic_fetch_add(&g_z[node][j0 + 1], acc.y, __ATOMIC_RELAXED, AGT);
      __hip_atomic_fetch_add(&g_z[node][j0 + 2], acc.z, __ATOMIC_RELAXED, AGT);
      __hip_atomic_fetch_add(&g_z[node][j0 + 3], acc.w, __ATOMIC_RELAXED, AGT);
    }
    grid_bar(L);  // level complete everywhere; no cache flush
  }

  // ---- Output: root z (root is always internal) ----
  if (blockIdx.x == 0) {
    float4 v;
    v.x = AL(&g_z[ROOT][j0 + 0]);
    v.y = AL(&g_z[ROOT][j0 + 1]);
    v.z = AL(&g_z[ROOT][j0 + 2]);
    v.w = AL(&g_z[ROOT][j0 + 3]);
    *(float4*)(out + j0) = v;
  }
  grid_bar(nlev + 1);  // output read before anyone zeroes g_z

  // ---- Cleanup: leave all device state zeroed for the next replay ----
  float* zf = &g_z[0][0];
  for (int k = blockIdx.x * 256 + tid; k < NN * DD; k += NB * 256) ASR(&zf[k], 0.f);
  grid_collect();
}

extern "C" void kernel_launch(void* const* d_in, const int* in_sizes, int n_in,
                              void* d_out, int out_size, void* d_ws, size_t ws_size,
                              hipStream_t stream) {
  const float* emb = (const float*)d_in[0];
  const float* par = (const float*)d_in[1];
  const int* cidx = (const int*)d_in[2];
  const int* cdep = (const int*)d_in[3];
  const unsigned char* cmask = (const unsigned char*)d_in[4];
  float* out = (float*)d_out;

  hipLaunchKernelGGL(dep_enc_kernel, dim3(NB), dim3(256), 0, stream, emb, par,
                     cidx, cdep, cmask, out);
}

// Round 7
// 454.727 us; speedup vs baseline: 3.4320x; 1.5601x over previous
//
#include <hip/hip_runtime.h>
#include <cstddef>

#define NN 256
#define DD 1024
#define CC 4
#define RS 32              // row-split units per node
#define ROWS (DD / RS)     // 32 rows per unit
#define NB 448             // <= 2 blocks/CU capacity -> all blocks resident
#define LEAVES 32
#define LQUOTA (NB / LEAVES)  // 14 arrivals per leaf counter
#define ROOT (NN - 1)
#define AGT __HIP_MEMORY_SCOPE_AGENT

// Static device scratch. ALL of it is left zeroed at kernel exit (g_z by the
// cleanup stage, counters/gens by the last arriver), so replays start clean.
__device__ float g_z[NN][DD];          // accumulated z per node (1 MB)
__device__ int g_bar_leaf[LEAVES];     // barrier leaf arrival counters
__device__ int g_bar_root;             // barrier root counter
__device__ int g_gen[LEAVES][32];      // per-leaf generation words (128B apart)

#define AL(p) __hip_atomic_load((p), __ATOMIC_RELAXED, AGT)
#define ASR(p, v) __hip_atomic_store((p), (v), __ATOMIC_RELAXED, AGT)

__device__ __forceinline__ void grid_bar(int gen, int leaf) {
  __syncthreads();  // all waves' vmem (incl. atomics) drained before arrival
  if (threadIdx.x == 0) {
    int lo = __hip_atomic_fetch_add(&g_bar_leaf[leaf], 1, __ATOMIC_RELAXED, AGT);
    if (lo == LQUOTA - 1) {
      int ro = __hip_atomic_fetch_add(&g_bar_root, 1, __ATOMIC_RELAXED, AGT);
      if (ro == LEAVES - 1) {
        // last block: reset counters, then flip all gen words (release:
        // resets + all prior work visible before any flip is observed)
        for (int i = 0; i < LEAVES; ++i) ASR(&g_bar_leaf[i], 0);
        ASR(&g_bar_root, 0);
        for (int i = 0; i < LEAVES; ++i)
          __hip_atomic_store(&g_gen[i][0], gen, __ATOMIC_RELEASE, AGT);
      } else {
        while (AL(&g_gen[leaf][0]) < gen) __builtin_amdgcn_s_sleep(2);
      }
    } else {
      while (AL(&g_gen[leaf][0]) < gen) __builtin_amdgcn_s_sleep(2);
    }
  }
  __syncthreads();
}

__device__ __forceinline__ void grid_collect(int leaf) {  // final: reset, no wait
  __syncthreads();
  if (threadIdx.x == 0) {
    int lo = __hip_atomic_fetch_add(&g_bar_leaf[leaf], 1, __ATOMIC_RELAXED, AGT);
    if (lo == LQUOTA - 1) {
      int ro = __hip_atomic_fetch_add(&g_bar_root, 1, __ATOMIC_RELAXED, AGT);
      if (ro == LEAVES - 1) {
        for (int i = 0; i < LEAVES; ++i) ASR(&g_bar_leaf[i], 0);
        ASR(&g_bar_root, 0);
        for (int i = 0; i < LEAVES; ++i) ASR(&g_gen[i][0], 0);
      }
    }
  }
}

__device__ __forceinline__ float4 relu4(float4 v) {
  float4 r;
  r.x = fmaxf(v.x, 0.f); r.y = fmaxf(v.y, 0.f);
  r.z = fmaxf(v.z, 0.f); r.w = fmaxf(v.w, 0.f);
  return r;
}

template <int NC>
__device__ __forceinline__ float4 run_rows(const float* const* pp, const float4* uu,
                                           const float* xs) {
  float4 acc = {0.f, 0.f, 0.f, 0.f};
#pragma unroll 8
  for (int r = 0; r < ROWS; ++r) {
    float4 a0 = *(const float4*)(pp[0] + (size_t)r * DD);
    float4 m;
    m.x = a0.x * uu[0].x; m.y = a0.y * uu[0].y;
    m.z = a0.z * uu[0].z; m.w = a0.w * uu[0].w;
#pragma unroll
    for (int c = 1; c < NC; ++c) {
      float4 a = *(const float4*)(pp[c] + (size_t)r * DD);
      m.x = fmaxf(m.x, a.x * uu[c].x);
      m.y = fmaxf(m.y, a.y * uu[c].y);
      m.z = fmaxf(m.z, a.z * uu[c].z);
      m.w = fmaxf(m.w, a.w * uu[c].w);
    }
    const float xr = xs[r];
    acc.x = fmaf(xr, m.x, acc.x);
    acc.y = fmaf(xr, m.y, acc.y);
    acc.z = fmaf(xr, m.z, acc.z);
    acc.w = fmaf(xr, m.w, acc.w);
  }
  return acc;
}

__global__ __launch_bounds__(256, 2) void dep_enc_kernel(
    const float* __restrict__ emb, const float* __restrict__ par,
    const int* __restrict__ cidx, const int* __restrict__ cdep,
    const unsigned char* __restrict__ cmask, float* __restrict__ out) {
  __shared__ int s_ci[NN][CC];
  __shared__ int s_cd[NN][CC];
  __shared__ int s_nc[NN];
  __shared__ int s_lvl[NN];
  __shared__ int s_cur[NN];
  __shared__ int s_lst[NN + 2];
  __shared__ unsigned char s_reach[NN];
  __shared__ short s_ord[NN];
  __shared__ int s_nlev;
  __shared__ int s_flag;
  __shared__ float xs[ROWS];

  const int tid = threadIdx.x;
  const int leaf = blockIdx.x & (LEAVES - 1);

  // Start-of-launch acquire: buffer_inv kills stale cross-launch L2 copies of
  // g_z, making later PLAIN cached loads of g_z safe.
  if (tid == 0) {
    int dmy = __hip_atomic_load(&g_bar_root, __ATOMIC_ACQUIRE, AGT);
    asm volatile("" ::"v"(dmy));
  }

  // ---- Phase 1 (redundant per block): schedule build in LDS ----
  if (tid == 0)
    s_flag = (cmask[1021] == 1 && cmask[1022] == 1 && cmask[1023] == 1);
  __syncthreads();
  const bool m_u8 = (s_flag != 0);
  const int* m32 = (const int*)cmask;
  const int i = tid;  // one node per thread
  int nc = 0;
#pragma unroll
  for (int c = 0; c < CC; ++c) {
    bool mk = m_u8 ? (cmask[i * CC + c] != 0) : (m32[i * CC + c] != 0);
    if (mk) {
      s_ci[i][nc] = cidx[i * CC + c];
      s_cd[i][nc] = cdep[i * CC + c];
      ++nc;
    }
  }
  s_nc[i] = nc;
  s_lvl[i] = 0;
  s_reach[i] = (i == ROOT) ? 1 : 0;
  __syncthreads();

  // Level fixpoint (monotone; converges in <= depth passes)
  for (int it = 0; it < NN + 2; ++it) {
    if (tid == 0) s_flag = 0;
    __syncthreads();
    if (nc) {
      int lv = 0;
      for (int c = 0; c < nc; ++c) lv = max(lv, s_lvl[s_ci[i][c]]);
      lv += 1;
      if (lv != s_lvl[i]) { s_lvl[i] = lv; s_flag = 1; }
    }
    __syncthreads();
    int ch = s_flag;
    __syncthreads();
    if (!ch) break;
  }

  // Reachability fixpoint (root downward)
  for (int it = 0; it < NN + 2; ++it) {
    if (tid == 0) s_flag = 0;
    __syncthreads();
    if (s_reach[i] && nc) {
      for (int c = 0; c < nc; ++c)
        if (!s_reach[s_ci[i][c]]) { s_reach[s_ci[i][c]] = 1; s_flag = 1; }
    }
    __syncthreads();
    int ch = s_flag;
    __syncthreads();
    if (!ch) break;
  }

  // Deterministic bucket build (tid0 serial over LDS; identical in every block)
  if (tid == 0) {
    for (int L = 0; L < NN + 2; ++L) s_lst[L] = 0;
    int maxl = 0;
    for (int n = 0; n < NN; ++n)
      if (s_reach[n] && s_nc[n] > 0) {
        s_lst[s_lvl[n] + 1]++;
        if (s_lvl[n] > maxl) maxl = s_lvl[n];
      }
    for (int L = 1; L <= maxl + 1; ++L) s_lst[L] += s_lst[L - 1];
    for (int L = 0; L <= maxl + 1; ++L) s_cur[L] = s_lst[L];
    for (int n = 0; n < NN; ++n)
      if (s_reach[n] && s_nc[n] > 0) s_ord[s_cur[s_lvl[n]]++] = (short)n;
    s_nlev = maxl;
  }
  __syncthreads();
  const int nlev = s_nlev;
  const int j0 = tid << 2;  // 4 consecutive columns per thread

  // ---- Phase 2: level-synchronized sweep with cheap barriers ----
  for (int L = 1; L <= nlev; ++L) {
    const int s = s_lst[L];
    const int nunits = (s_lst[L + 1] - s) << 5;  // RS units per node
    for (int g = blockIdx.x; g < nunits; g += NB) {
      const int node = s_ord[s + (g >> 5)];
      const int rblk = g & (RS - 1);
      const int nnc = s_nc[node];

      __syncthreads();  // xs from previous unit fully consumed
      if (tid < ROWS) xs[tid] = emb[(size_t)node * DD + rblk * ROWS + tid];

      // Gather relu(z_child): plain cached coalesced loads (safe: see inv above)
      float4 uu[CC];
      const float* pp[CC];
      const size_t rb = (size_t)(rblk * ROWS) * DD + j0;
#pragma unroll
      for (int c = 0; c < CC; ++c) {
        if (c < nnc) {
          const int chd = s_ci[node][c];
          pp[c] = par + (size_t)s_cd[node][c] * (DD * DD) + rb;
          float4 sz;
          if (s_nc[chd] == 0) {
            sz = *(const float4*)(emb + (size_t)chd * DD + j0);
          } else {
            sz = *(const float4*)(&g_z[chd][j0]);
          }
          uu[c] = relu4(sz);
        }
      }
      __syncthreads();  // xs ready

      float4 acc;
      switch (nnc) {
        case 1: acc = run_rows<1>(pp, uu, xs); break;
        case 2: acc = run_rows<2>(pp, uu, xs); break;
        case 3: acc = run_rows<3>(pp, uu, xs); break;
        default: acc = run_rows<4>(pp, uu, xs); break;
      }
      // Accumulate partial into z at the memory-side coherence point
      __hip_atomic_fetch_add(&g_z[node][j0 + 0], acc.x, __ATOMIC_RELAXED, AGT);
      __hip_atomic_fetch_add(&g_z[node][j0 + 1], acc.y, __ATOMIC_RELAXED, AGT);
      __hip_atomic_fetch_add(&g_z[node][j0 + 2], acc.z, __ATOMIC_RELAXED, AGT);
      __hip_atomic_fetch_add(&g_z[node][j0 + 3], acc.w, __ATOMIC_RELAXED, AGT);
    }
    grid_bar(L, leaf);  // level complete everywhere; no cache flush
  }

  // ---- Output: root z (root is always internal) ----
  if (blockIdx.x == 0) {
    float4 v = *(const float4*)(&g_z[ROOT][j0]);
    *(float4*)(out + j0) = v;
  }
  grid_bar(nlev + 1, leaf);  // output read before anyone zeroes g_z

  // ---- Cleanup: leave all device state zeroed for the next replay ----
  float* zf = &g_z[0][0];
  for (int k = blockIdx.x * 256 + tid; k < NN * DD; k += NB * 256) ASR(&zf[k], 0.f);
  grid_collect(leaf);
}

extern "C" void kernel_launch(void* const* d_in, const int* in_sizes, int n_in,
                              void* d_out, int out_size, void* d_ws, size_t ws_size,
                              hipStream_t stream) {
  const float* emb = (const float*)d_in[0];
  const float* par = (const float*)d_in[1];
  const int* cidx = (const int*)d_in[2];
  const int* cdep = (const int*)d_in[3];
  const unsigned char* cmask = (const unsigned char*)d_in[4];
  float* out = (float*)d_out;

  hipLaunchKernelGGL(dep_enc_kernel, dim3(NB), dim3(256), 0, stream, emb, par,
                     cidx, cdep, cmask, out);
}

// Round 8
// 319.107 us; speedup vs baseline: 4.8906x; 1.4250x over previous
//
#include <hip/hip_runtime.h>
#include <cstddef>

#define NN 256
#define DD 1024
#define CC 4
#define RS 32              // row-split units per node
#define ROWS (DD / RS)     // 32 rows per unit
#define NB 448             // <= 2 blocks/CU capacity -> all blocks resident
#define ROOT (NN - 1)
#define AGT __HIP_MEMORY_SCOPE_AGENT

// Static device scratch. g_zp/g_z are fully REWRITTEN (stores, not adds) for
// every active node each launch; g_done/g_rdy are reset to zero by the root
// finisher, so every launch/graph-replay starts clean.
__device__ float g_zp[NN][RS][DD];  // row-partial z (32 MB, write-through)
__device__ float g_z[NN][DD];       // reduced z per node (1 MB, write-through)
__device__ int g_done[NN];          // completed units per node (0..RS)
__device__ int g_rdy[NN];           // node reduced & published

#define AL(p) __hip_atomic_load((p), __ATOMIC_RELAXED, AGT)
#define ASR(p, v) __hip_atomic_store((p), (v), __ATOMIC_RELAXED, AGT)

__device__ __forceinline__ float4 relu4(float4 v) {
  float4 r;
  r.x = fmaxf(v.x, 0.f); r.y = fmaxf(v.y, 0.f);
  r.z = fmaxf(v.z, 0.f); r.w = fmaxf(v.w, 0.f);
  return r;
}

template <int NC>
__device__ __forceinline__ float4 run_rows(const float* const* pp, const float4* uu,
                                           const float* xs) {
  float4 acc = {0.f, 0.f, 0.f, 0.f};
#pragma unroll 8
  for (int r = 0; r < ROWS; ++r) {
    float4 a0 = *(const float4*)(pp[0] + (size_t)r * DD);
    float4 m;
    m.x = a0.x * uu[0].x; m.y = a0.y * uu[0].y;
    m.z = a0.z * uu[0].z; m.w = a0.w * uu[0].w;
#pragma unroll
    for (int c = 1; c < NC; ++c) {
      float4 a = *(const float4*)(pp[c] + (size_t)r * DD);
      m.x = fmaxf(m.x, a.x * uu[c].x);
      m.y = fmaxf(m.y, a.y * uu[c].y);
      m.z = fmaxf(m.z, a.z * uu[c].z);
      m.w = fmaxf(m.w, a.w * uu[c].w);
    }
    const float xr = xs[r];
    acc.x = fmaf(xr, m.x, acc.x);
    acc.y = fmaf(xr, m.y, acc.y);
    acc.z = fmaf(xr, m.z, acc.z);
    acc.w = fmaf(xr, m.w, acc.w);
  }
  return acc;
}

__global__ __launch_bounds__(256, 2) void dep_enc_kernel(
    const float* __restrict__ emb, const float* __restrict__ par,
    const int* __restrict__ cidx, const int* __restrict__ cdep,
    const unsigned char* __restrict__ cmask, float* __restrict__ out) {
  __shared__ int s_ci[NN][CC];
  __shared__ int s_cd[NN][CC];
  __shared__ int s_nc[NN];
  __shared__ int s_pfx[NN];
  __shared__ unsigned char s_reach[NN];
  __shared__ short s_int[NN];  // internal reachable nodes, ascending (= topo)
  __shared__ int s_NI;
  __shared__ int s_flag;
  __shared__ int s_fin;
  __shared__ float xs[ROWS];

  const int tid = threadIdx.x;

  // Start-of-launch acquire: buffer_inv kills stale cross-launch L2 copies of
  // g_zp/g_z, making later PLAIN cached loads of them safe (first touch of
  // every line within a launch happens after its publish).
  if (tid == 0) {
    int dmy = __hip_atomic_load(&g_done[0], __ATOMIC_ACQUIRE, AGT);
    asm volatile("" ::"v"(dmy));
  }

  // ---- Phase 1 (redundant per block, ~8 us): compact children + prune ----
  if (tid == 0)
    s_flag = (cmask[1021] == 1 && cmask[1022] == 1 && cmask[1023] == 1);
  __syncthreads();
  const bool m_u8 = (s_flag != 0);
  const int* m32 = (const int*)cmask;
  const int i = tid;  // one node per thread
  int nc = 0;
#pragma unroll
  for (int c = 0; c < CC; ++c) {
    bool mk = m_u8 ? (cmask[i * CC + c] != 0) : (m32[i * CC + c] != 0);
    if (mk) {
      s_ci[i][nc] = cidx[i * CC + c];
      s_cd[i][nc] = cdep[i * CC + c];
      ++nc;
    }
  }
  s_nc[i] = nc;
  s_reach[i] = (i == ROOT) ? 1 : 0;
  __syncthreads();

  // Reachability fixpoint (root downward; converges in <= depth passes)
  for (int it = 0; it < NN + 2; ++it) {
    if (tid == 0) s_flag = 0;
    __syncthreads();
    if (s_reach[i] && nc) {
      for (int c = 0; c < nc; ++c)
        if (!s_reach[s_ci[i][c]]) { s_reach[s_ci[i][c]] = 1; s_flag = 1; }
    }
    __syncthreads();
    int ch = s_flag;
    __syncthreads();
    if (!ch) break;
  }

  // Parallel compaction of internal reachable nodes (ascending index = topo)
  const int active = (s_reach[i] && nc > 0) ? 1 : 0;
  s_pfx[i] = active;
  __syncthreads();
  for (int off = 1; off < NN; off <<= 1) {
    int v = (tid >= off) ? s_pfx[tid - off] : 0;
    __syncthreads();
    s_pfx[tid] += v;
    __syncthreads();
  }
  if (active) s_int[s_pfx[i] - 1] = (short)i;
  if (tid == NN - 1) s_NI = s_pfx[NN - 1];
  __syncthreads();

  const int NU = s_NI << 5;  // RS units per internal node
  const int j0 = tid << 2;   // 4 consecutive columns per thread

  // ---- Phase 2: event-driven units, topological static assignment ----
  for (int g = blockIdx.x; g < NU; g += NB) {
    const int node = s_int[g >> 5];
    const int rblk = g & (RS - 1);
    const int nnc = s_nc[node];

    // xs load overlaps the dependency poll (prev unit fully done at this point)
    if (tid < ROWS) xs[tid] = emb[(size_t)node * DD + rblk * ROWS + tid];
    // Poll children readiness (one thread per child; relaxed -> no cache inv)
    if (tid < nnc) {
      const int chd = s_ci[node][tid];
      if (s_nc[chd] > 0) {
        while (AL(&g_rdy[chd]) == 0) __builtin_amdgcn_s_sleep(1);
      }
    }
    __syncthreads();  // (A) children ready + xs visible

    // Gather relu(z_child): plain cached coalesced loads (fresh: see inv note)
    float4 uu[CC];
    const float* pp[CC];
    const size_t rb = (size_t)(rblk * ROWS) * DD + j0;
#pragma unroll
    for (int c = 0; c < CC; ++c) {
      if (c < nnc) {
        const int chd = s_ci[node][c];
        pp[c] = par + (size_t)s_cd[node][c] * (DD * DD) + rb;
        float4 sz;
        if (s_nc[chd] == 0) {
          sz = *(const float4*)(emb + (size_t)chd * DD + j0);
        } else {
          sz = *(const float4*)(&g_z[chd][j0]);
        }
        uu[c] = relu4(sz);
      }
    }

    float4 acc;
    switch (nnc) {
      case 1: acc = run_rows<1>(pp, uu, xs); break;
      case 2: acc = run_rows<2>(pp, uu, xs); break;
      case 3: acc = run_rows<3>(pp, uu, xs); break;
      default: acc = run_rows<4>(pp, uu, xs); break;
    }
    // Publish partial (write-through; no L2 allocate)
    ASR(&g_zp[node][rblk][j0 + 0], acc.x);
    ASR(&g_zp[node][rblk][j0 + 1], acc.y);
    ASR(&g_zp[node][rblk][j0 + 2], acc.z);
    ASR(&g_zp[node][rblk][j0 + 3], acc.w);
    __syncthreads();  // (B) all waves' stores drained (vmcnt 0)

    if (tid == 0) {
      int old = __hip_atomic_fetch_add(&g_done[node], 1, __ATOMIC_RELEASE, AGT);
      s_fin = (old == RS - 1) ? 1 : 0;
    }
    __syncthreads();  // (C)

    if (s_fin) {
      // Finisher: fixed-order reduce of RS partials (deterministic), publish.
      const float* zb = &g_zp[node][0][j0];
      float4 v = {0.f, 0.f, 0.f, 0.f};
#pragma unroll
      for (int p = 0; p < RS; ++p) {
        float4 t = *(const float4*)(zb + (size_t)p * DD);
        v.x += t.x; v.y += t.y; v.z += t.z; v.w += t.w;
      }
      if (node == ROOT) {
        *(float4*)(out + j0) = v;
        // Root done => (pruned DAG) every unit done; nobody reads flags again.
        ASR(&g_done[tid], 0);
        ASR(&g_rdy[tid], 0);
      } else {
        ASR(&g_z[node][j0 + 0], v.x);
        ASR(&g_z[node][j0 + 1], v.y);
        ASR(&g_z[node][j0 + 2], v.z);
        ASR(&g_z[node][j0 + 3], v.w);
        __syncthreads();  // (D) publish drained before rdy flips
        if (tid == 0)
          __hip_atomic_fetch_add(&g_rdy[node], 1, __ATOMIC_RELEASE, AGT);
      }
    }
  }
}

extern "C" void kernel_launch(void* const* d_in, const int* in_sizes, int n_in,
                              void* d_out, int out_size, void* d_ws, size_t ws_size,
                              hipStream_t stream) {
  const float* emb = (const float*)d_in[0];
  const float* par = (const float*)d_in[1];
  const int* cidx = (const int*)d_in[2];
  const int* cdep = (const int*)d_in[3];
  const unsigned char* cmask = (const unsigned char*)d_in[4];
  float* out = (float*)d_out;

  hipLaunchKernelGGL(dep_enc_kernel, dim3(NB), dim3(256), 0, stream, emb, par,
                     cidx, cdep, cmask, out);
}